// Round 10
// baseline (540.575 us; speedup 1.0000x reference)
//
#include <hip/hip_runtime.h>

// CRITICAL: hipcc defaults to -ffp-contract=fast-honor-pragmas, and HIP's
// __fmul_rn/__fadd_rn are PLAIN OPERATORS (not contraction barriers like
// CUDA). This pragma guarantees mul/add are not fused into v_fmac/v_pk_fma,
// so our rounding matches numpy's exactly. (R4 proved this: absmax == 0.0.)
#pragma clang fp contract(off)

typedef float v2f __attribute__((ext_vector_type(2)));

// Forced packed fp32 (VOP3P): per-component rounding == scalar v_mul/v_add.
static __device__ __forceinline__ v2f pk_mul(v2f a, v2f b) {
    v2f d;
    asm("v_pk_mul_f32 %0, %1, %2" : "=v"(d) : "v"(a), "v"(b));
    return d;
}
static __device__ __forceinline__ v2f pk_add(v2f a, v2f b) {
    v2f d;
    asm("v_pk_add_f32 %0, %1, %2" : "=v"(d) : "v"(a), "v"(b));
    return d;
}
static __device__ __forceinline__ float min3f(float a, float b, float c) {
    float d;
    asm("v_min3_f32 %0, %1, %2, %3" : "=v"(d) : "v"(a), "v"(b), "v"(c));
    return d;
}

// Problem constants (from reference): B=4, N=16384, M=4096, D=64
#define MM 4096
#define DD 64
#define BN 65536                  // B*N points
#define FEATS_OFF 0               // feats: BN*DD floats
#define IDS_OFF (BN * DD)         // ids:   BN floats (ints stored as float)
#define PC_OFF (IDS_OFF + BN)     // pc:    BN*3 floats passthrough

#define BLK 512                   // threads per block (8 waves)
#define CC 32                     // lanes per point
#define PP 8                      // points per thread (register tile)
#define PPB 128                   // points per block (BLK*PP/CC)
#define NPG (BN / PPB)            // 512 point-groups
#define HPAIR 1024                // key pairs per half (2048 keys)
#define KIT (HPAIR / CC)          // 32 main-loop iterations

// NUMERICS (bit-exact vs numpy fp32 replay — verified R4-R9, absmax==0):
//  - keys stored NEGATED+DOUBLED: rn commutes with sign/2^k scaling, so
//    d2 = (psq + cross') + ksq == (psq - 2*cross) + ksq == reference bits.
//  - all plain rn (contract off); k_sq/p_sq ascending plain; pk per-lane
//    rounding == scalar. argmin: min3 strict-drop keeps first iter; even
//    key preferred on within-pair tie; lexicographic (d2,id) merges
//    (butterfly + cross-half) => numpy first-index tie-break.
//
// STRUCTURE (R10): R9 showed ~23 us VALU-idle at 4 waves/SIMD (64 KiB LDS
// pinned occupancy). Split keys in HALVES: 32 KiB LDS/block -> 3-4 blocks/CU
// = 6-8 waves/SIMD. Each block writes its half's per-point (d2,id) champion
// to workspace; kernel2 merges halves exactly + gathers values + pc copy.
// LDS reads software-pipelined (prefetch next iter before compute).
__global__ __launch_bounds__(BLK, 7)
void quant_scan_kernel(const float* __restrict__ pc,
                       const float* __restrict__ keys,
                       float* __restrict__ bdws,
                       int* __restrict__ bmws)
{
#pragma clang fp contract(off)
    __shared__ float4 skA[HPAIR];  // (-2kx_e,-2kx_o,-2ky_e,-2ky_o) 16 KiB
    __shared__ float4 skB[HPAIR];  // (-2kz_e,-2kz_o, ksq_e, ksq_o) 16 KiB

    const int tid = threadIdx.x;
    const int pg   = blockIdx.x & (NPG - 1);   // point-group 0..511
    const int half = blockIdx.x >> 9;          // key-half 0 or 1

    // Stage this half's key pairs (2/thread). Global pair jg = half*1024+jl;
    // pair = keys 2jg (f0.x,f0.y,f1.x) and 2jg+1 (f1.y,f2.x,f2.y).
    #pragma unroll
    for (int i = 0; i < HPAIR / BLK; ++i) {
        const int jl = tid + i * BLK;
        const int jg = (half << 10) + jl;
        const float2 f0 = ((const float2*)keys)[3 * jg + 0];
        const float2 f1 = ((const float2*)keys)[3 * jg + 1];
        const float2 f2 = ((const float2*)keys)[3 * jg + 2];
        const float ksq0 = ((f0.x * f0.x) + (f0.y * f0.y)) + (f1.x * f1.x);
        const float ksq1 = ((f1.y * f1.y) + (f2.x * f2.x)) + (f2.y * f2.y);
        skA[jl] = make_float4(-2.0f * f0.x, -2.0f * f1.y,
                              -2.0f * f0.y, -2.0f * f2.x);
        skB[jl] = make_float4(-2.0f * f1.x, -2.0f * f2.y, ksq0, ksq1);
    }

    const int c = tid & (CC - 1);
    const int g = tid >> 5;                    // point-group-local 0..15
    const int p0 = pg * PPB + g * PP;          // my first point

    // Load my 8 points (24 floats = 6 float4, aligned: 3*p0 % 4 == 0).
    float arr[24];
    {
        const float4* pcv = (const float4*)(pc + 3 * p0);
        #pragma unroll
        for (int i = 0; i < 6; ++i) ((float4*)arr)[i] = pcv[i];
    }
    v2f PX[PP], PY[PP], PZ[PP], PSQ[PP];
    float bd[PP];
    int bk[PP];
    #pragma unroll
    for (int i = 0; i < PP; ++i) {
        const float px = arr[3 * i + 0];
        const float py = arr[3 * i + 1];
        const float pz = arr[3 * i + 2];
        const float psq = ((px * px) + (py * py)) + (pz * pz);
        PX[i] = (v2f){px, px};
        PY[i] = (v2f){py, py};
        PZ[i] = (v2f){pz, pz};
        PSQ[i] = (v2f){psq, psq};
        bd[i] = 3.402823466e38f;
        bk[i] = 0;
    }

    __syncthreads();

    // Main loop over this half: lane c, iter k -> local pair jl = 32k + c.
    // Software pipeline: prefetch iter k+1's LDS values before computing k.
    float4 A  = skA[c];
    float4 Bv = skB[c];
    #pragma unroll 2
    for (int k = 0; k < KIT; ++k) {
        const int jn = (((k + 1) & (KIT - 1)) << 5) + c;
        const float4 An = skA[jn];
        const float4 Bn = skB[jn];
        const v2f Kx = {A.x,  A.y};
        const v2f Ky = {A.z,  A.w};
        const v2f Kz = {Bv.x, Bv.y};
        const v2f Ks = {Bv.z, Bv.w};
        #pragma unroll
        for (int i = 0; i < PP; ++i) {
            v2f t = pk_add(pk_mul(Kx, PX[i]), pk_mul(Ky, PY[i]));
            t = pk_add(t, pk_mul(Kz, PZ[i]));
            t = pk_add(PSQ[i], t);       // psq - 2*cross (keys negated)
            t = pk_add(t, Ks);           // + ksq
            const float nb = min3f(bd[i], t.x, t.y);
            const bool ch = nb < bd[i];  // strict drop => first-index kept
            bd[i] = nb;
            bk[i] = ch ? k : bk[i];
        }
        A = An;
        Bv = Bn;
    }

    // Recover winning key within pair bk[i] (scalar plain == pk bits), then
    // butterfly-merge the 32 lanes; lane 0 writes this half's champion.
    #pragma unroll
    for (int i = 0; i < PP; ++i) {
        const int jl = (bk[i] << 5) + c;
        const float4 Ar = skA[jl];
        const float4 Br = skB[jl];
        const float ca = ((PX[i].x * Ar.x) + (PY[i].x * Ar.z)) + (PZ[i].x * Br.x);
        const float da = (PSQ[i].x + ca) + Br.z;
        const int m0 = (((half << 10) + jl) << 1);
        float d = bd[i];
        int   m = (da == bd[i]) ? m0 : (m0 + 1);  // even preferred on tie
        #pragma unroll
        for (int off = 1; off < CC; off <<= 1) {
            const float od = __shfl_xor(d, off);
            const int   om = __shfl_xor(m, off);
            if (od < d || (od == d && om < m)) { d = od; m = om; }
        }
        if (c == 0) {
            bdws[half * BN + p0 + i] = d;
            bmws[half * BN + p0 + i] = m;
        }
    }
}

// Kernel 2: merge the two halves (exact fp32 lexicographic), gather value
// rows, write feats + ids, and copy the pc passthrough.
__global__ __launch_bounds__(256)
void merge_gather_kernel(const float* __restrict__ pc,
                         const float* __restrict__ values,
                         const float* __restrict__ bdws,
                         const int* __restrict__ bmws,
                         float* __restrict__ out)
{
    const int tid = threadIdx.x;
    const int c = tid & 15;                       // lane within point
    const int p = blockIdx.x * 16 + (tid >> 4);   // point id

    const float d0 = bdws[p];
    const float d1 = bdws[BN + p];
    const int   m0 = bmws[p];
    const int   m1 = bmws[BN + p];
    // Half-0 ids are all smaller than half-1 ids, so on exact tie keep m0.
    const int m = (d1 < d0) ? m1 : m0;

    const float4 v = ((const float4*)(values + (size_t)m * DD))[c];
    ((float4*)(out + FEATS_OFF + (size_t)p * DD))[c] = v;
    if (c == 0) out[IDS_OFF + p] = (float)m;

    // pc passthrough: 196608 floats = 49152 float4 spread over the grid.
    const int gt = blockIdx.x * 256 + tid;
    if (gt < BN * 3 / 4) {
        ((float4*)(out + PC_OFF))[gt] = ((const float4*)pc)[gt];
    }
}

extern "C" void kernel_launch(void* const* d_in, const int* in_sizes, int n_in,
                              void* d_out, int out_size, void* d_ws, size_t ws_size,
                              hipStream_t stream) {
    const float* pc     = (const float*)d_in[0];
    const float* keys   = (const float*)d_in[1];
    const float* values = (const float*)d_in[2];
    float* out = (float*)d_out;

    float* bdws = (float*)d_ws;                  // 2*BN floats
    int*   bmws = (int*)d_ws + 2 * BN;           // 2*BN ints   (1 MB total)

    quant_scan_kernel<<<dim3(2 * NPG), dim3(BLK), 0, stream>>>(pc, keys, bdws, bmws);
    merge_gather_kernel<<<dim3(BN / 16), dim3(256), 0, stream>>>(pc, values, bdws, bmws, out);
}

// Round 11
// 455.813 us; speedup vs baseline: 1.1860x; 1.1860x over previous
//
#include <hip/hip_runtime.h>

// CRITICAL: hipcc defaults to -ffp-contract=fast-honor-pragmas, and HIP's
// __fmul_rn/__fadd_rn are PLAIN OPERATORS (not contraction barriers like
// CUDA). This pragma guarantees mul/add are not fused into v_fmac/v_pk_fma,
// so our rounding matches numpy's exactly. (R4 proved this: absmax == 0.0.)
#pragma clang fp contract(off)

typedef float v2f __attribute__((ext_vector_type(2)));

// Forced packed fp32 (VOP3P): per-component rounding == scalar v_mul/v_add.
static __device__ __forceinline__ v2f pk_mul(v2f a, v2f b) {
    v2f d;
    asm("v_pk_mul_f32 %0, %1, %2" : "=v"(d) : "v"(a), "v"(b));
    return d;
}
static __device__ __forceinline__ v2f pk_add(v2f a, v2f b) {
    v2f d;
    asm("v_pk_add_f32 %0, %1, %2" : "=v"(d) : "v"(a), "v"(b));
    return d;
}
static __device__ __forceinline__ float min3f(float a, float b, float c) {
    float d;
    asm("v_min3_f32 %0, %1, %2, %3" : "=v"(d) : "v"(a), "v"(b), "v"(c));
    return d;
}

// Problem constants (from reference): B=4, N=16384, M=4096, D=64
#define MM 4096
#define DD 64
#define BN 65536                  // B*N points
#define FEATS_OFF 0               // feats: BN*DD floats
#define IDS_OFF (BN * DD)         // ids:   BN floats (ints stored as float)
#define PC_OFF (IDS_OFF + BN)     // pc:    BN*3 floats passthrough

#define BLK 512                   // threads per block (8 waves)
#define CC 32                     // lanes per point
#define PP 8                      // points per thread (register tile)
#define PPB 128                   // points per block (BLK*PP/CC)
#define NPG (BN / PPB)            // 512 point-groups
#define HPAIR 1024                // key pairs per half (2048 keys)
#define KIT (HPAIR / CC)          // 32 main-loop iterations

// NUMERICS (bit-exact vs numpy fp32 replay — verified R4-R10, absmax==0):
//  - keys stored NEGATED+DOUBLED: rn commutes with sign/2^k scaling, so
//    d2 = (psq + cross') + ksq == (psq - 2*cross) + ksq == reference bits.
//  - all plain rn (contract off); k_sq/p_sq ascending plain; pk per-lane
//    rounding == scalar. argmin: min3 strict-drop keeps first iter; even
//    key preferred on within-pair tie; lexicographic (d2,id) merges
//    (butterfly + cross-half) => numpy first-index tie-break.
//
// STRUCTURE (R11): R10's idea (32 KiB key-halves -> 4 blocks/CU = 8
// waves/SIMD) was right but __launch_bounds__(512,7) capped VGPR at ~73 and
// spilled ALL per-thread state to scratch (VGPR 36, 1.5 GB spill traffic,
// VALUBusy 9%). Fix: min-waves 6 -> VGPR cap 84 >= natural 64. Occupancy is
// then set by real resources: threads 2048/512=4 blocks, LDS 128<=160 KiB
// -> 8 waves/SIMD. Grid 1024 = exactly 4 blocks/CU.
__global__ __launch_bounds__(BLK, 6)
void quant_scan_kernel(const float* __restrict__ pc,
                       const float* __restrict__ keys,
                       float* __restrict__ bdws,
                       int* __restrict__ bmws)
{
#pragma clang fp contract(off)
    __shared__ float4 skA[HPAIR];  // (-2kx_e,-2kx_o,-2ky_e,-2ky_o) 16 KiB
    __shared__ float4 skB[HPAIR];  // (-2kz_e,-2kz_o, ksq_e, ksq_o) 16 KiB

    const int tid = threadIdx.x;
    const int pg   = blockIdx.x & (NPG - 1);   // point-group 0..511
    const int half = blockIdx.x >> 9;          // key-half 0 or 1

    // Stage this half's key pairs (2/thread). Global pair jg = half*1024+jl;
    // pair = keys 2jg (f0.x,f0.y,f1.x) and 2jg+1 (f1.y,f2.x,f2.y).
    #pragma unroll
    for (int i = 0; i < HPAIR / BLK; ++i) {
        const int jl = tid + i * BLK;
        const int jg = (half << 10) + jl;
        const float2 f0 = ((const float2*)keys)[3 * jg + 0];
        const float2 f1 = ((const float2*)keys)[3 * jg + 1];
        const float2 f2 = ((const float2*)keys)[3 * jg + 2];
        const float ksq0 = ((f0.x * f0.x) + (f0.y * f0.y)) + (f1.x * f1.x);
        const float ksq1 = ((f1.y * f1.y) + (f2.x * f2.x)) + (f2.y * f2.y);
        skA[jl] = make_float4(-2.0f * f0.x, -2.0f * f1.y,
                              -2.0f * f0.y, -2.0f * f2.x);
        skB[jl] = make_float4(-2.0f * f1.x, -2.0f * f2.y, ksq0, ksq1);
    }

    const int c = tid & (CC - 1);
    const int g = tid >> 5;                    // point-group-local 0..15
    const int p0 = pg * PPB + g * PP;          // my first point

    // Load my 8 points (24 floats = 6 float4, aligned: 3*p0 % 4 == 0).
    float arr[24];
    {
        const float4* pcv = (const float4*)(pc + 3 * p0);
        #pragma unroll
        for (int i = 0; i < 6; ++i) ((float4*)arr)[i] = pcv[i];
    }
    v2f PX[PP], PY[PP], PZ[PP], PSQ[PP];
    float bd[PP];
    int bk[PP];
    #pragma unroll
    for (int i = 0; i < PP; ++i) {
        const float px = arr[3 * i + 0];
        const float py = arr[3 * i + 1];
        const float pz = arr[3 * i + 2];
        const float psq = ((px * px) + (py * py)) + (pz * pz);
        PX[i] = (v2f){px, px};
        PY[i] = (v2f){py, py};
        PZ[i] = (v2f){pz, pz};
        PSQ[i] = (v2f){psq, psq};
        bd[i] = 3.402823466e38f;
        bk[i] = 0;
    }

    __syncthreads();

    // Main loop over this half: lane c, iter k -> local pair jl = 32k + c.
    // Software pipeline: prefetch iter k+1's LDS values before computing k.
    float4 A  = skA[c];
    float4 Bv = skB[c];
    #pragma unroll 2
    for (int k = 0; k < KIT; ++k) {
        const int jn = (((k + 1) & (KIT - 1)) << 5) + c;
        const float4 An = skA[jn];
        const float4 Bn = skB[jn];
        const v2f Kx = {A.x,  A.y};
        const v2f Ky = {A.z,  A.w};
        const v2f Kz = {Bv.x, Bv.y};
        const v2f Ks = {Bv.z, Bv.w};
        #pragma unroll
        for (int i = 0; i < PP; ++i) {
            v2f t = pk_add(pk_mul(Kx, PX[i]), pk_mul(Ky, PY[i]));
            t = pk_add(t, pk_mul(Kz, PZ[i]));
            t = pk_add(PSQ[i], t);       // psq - 2*cross (keys negated)
            t = pk_add(t, Ks);           // + ksq
            const float nb = min3f(bd[i], t.x, t.y);
            const bool ch = nb < bd[i];  // strict drop => first-index kept
            bd[i] = nb;
            bk[i] = ch ? k : bk[i];
        }
        A = An;
        Bv = Bn;
    }

    // Recover winning key within pair bk[i] (scalar plain == pk bits), then
    // butterfly-merge the 32 lanes; lane 0 writes this half's champion.
    #pragma unroll
    for (int i = 0; i < PP; ++i) {
        const int jl = (bk[i] << 5) + c;
        const float4 Ar = skA[jl];
        const float4 Br = skB[jl];
        const float ca = ((PX[i].x * Ar.x) + (PY[i].x * Ar.z)) + (PZ[i].x * Br.x);
        const float da = (PSQ[i].x + ca) + Br.z;
        const int m0 = (((half << 10) + jl) << 1);
        float d = bd[i];
        int   m = (da == bd[i]) ? m0 : (m0 + 1);  // even preferred on tie
        #pragma unroll
        for (int off = 1; off < CC; off <<= 1) {
            const float od = __shfl_xor(d, off);
            const int   om = __shfl_xor(m, off);
            if (od < d || (od == d && om < m)) { d = od; m = om; }
        }
        if (c == 0) {
            bdws[half * BN + p0 + i] = d;
            bmws[half * BN + p0 + i] = m;
        }
    }
}

// Kernel 2: merge the two halves (exact fp32 lexicographic), gather value
// rows, write feats + ids, and copy the pc passthrough.
__global__ __launch_bounds__(256)
void merge_gather_kernel(const float* __restrict__ pc,
                         const float* __restrict__ values,
                         const float* __restrict__ bdws,
                         const int* __restrict__ bmws,
                         float* __restrict__ out)
{
    const int tid = threadIdx.x;
    const int c = tid & 15;                       // lane within point
    const int p = blockIdx.x * 16 + (tid >> 4);   // point id

    const float d0 = bdws[p];
    const float d1 = bdws[BN + p];
    const int   m0 = bmws[p];
    const int   m1 = bmws[BN + p];
    // Half-0 ids are all smaller than half-1 ids, so on exact tie keep m0.
    const int m = (d1 < d0) ? m1 : m0;

    const float4 v = ((const float4*)(values + (size_t)m * DD))[c];
    ((float4*)(out + FEATS_OFF + (size_t)p * DD))[c] = v;
    if (c == 0) out[IDS_OFF + p] = (float)m;

    // pc passthrough: 196608 floats = 49152 float4 spread over the grid.
    const int gt = blockIdx.x * 256 + tid;
    if (gt < BN * 3 / 4) {
        ((float4*)(out + PC_OFF))[gt] = ((const float4*)pc)[gt];
    }
}

extern "C" void kernel_launch(void* const* d_in, const int* in_sizes, int n_in,
                              void* d_out, int out_size, void* d_ws, size_t ws_size,
                              hipStream_t stream) {
    const float* pc     = (const float*)d_in[0];
    const float* keys   = (const float*)d_in[1];
    const float* values = (const float*)d_in[2];
    float* out = (float*)d_out;

    float* bdws = (float*)d_ws;                  // 2*BN floats
    int*   bmws = (int*)d_ws + 2 * BN;           // 2*BN ints   (1 MB total)

    quant_scan_kernel<<<dim3(2 * NPG), dim3(BLK), 0, stream>>>(pc, keys, bdws, bmws);
    merge_gather_kernel<<<dim3(BN / 16), dim3(256), 0, stream>>>(pc, values, bdws, bmws, out);
}

// Round 12
// 114.385 us; speedup vs baseline: 4.7259x; 3.9849x over previous
//
#include <hip/hip_runtime.h>

// CRITICAL: hipcc defaults to -ffp-contract=fast-honor-pragmas, and HIP's
// __fmul_rn/__fadd_rn are PLAIN OPERATORS (not contraction barriers like
// CUDA). This pragma guarantees mul/add are not fused into v_fmac/v_pk_fma,
// so our rounding matches numpy's exactly. (R4 proved this: absmax == 0.0.)
#pragma clang fp contract(off)

typedef float v2f __attribute__((ext_vector_type(2)));

// Forced packed fp32 (VOP3P): per-component rounding == scalar v_mul/v_add.
static __device__ __forceinline__ v2f pk_mul(v2f a, v2f b) {
    v2f d;
    asm("v_pk_mul_f32 %0, %1, %2" : "=v"(d) : "v"(a), "v"(b));
    return d;
}
static __device__ __forceinline__ v2f pk_add(v2f a, v2f b) {
    v2f d;
    asm("v_pk_add_f32 %0, %1, %2" : "=v"(d) : "v"(a), "v"(b));
    return d;
}
static __device__ __forceinline__ float min3f(float a, float b, float c) {
    float d;
    asm("v_min3_f32 %0, %1, %2, %3" : "=v"(d) : "v"(a), "v"(b), "v"(c));
    return d;
}

// Problem constants (from reference): B=4, N=16384, M=4096, D=64
#define MM 4096
#define DD 64
#define BN 65536                  // B*N points
#define FEATS_OFF 0               // feats: BN*DD floats
#define IDS_OFF (BN * DD)         // ids:   BN floats (ints stored as float)
#define PC_OFF (IDS_OFF + BN)     // pc:    BN*3 floats passthrough

#define BLK 512                   // threads per block (8 waves)
#define CC 32                     // lanes per point
#define PP 8                      // points per thread (register tile)
#define PPB 128                   // points per block (BLK*PP/CC)
#define NPG (BN / PPB)            // 512 point-groups
#define HPAIR 1024                // key pairs per half (2048 keys)
#define KIT (HPAIR / CC)          // 32 main-loop iterations

// NUMERICS (bit-exact vs numpy fp32 replay — verified R4-R11, absmax==0):
//  - keys stored NEGATED+DOUBLED: rn commutes with sign/2^k scaling, so
//    d2 = (psq + cross') + ksq == (psq - 2*cross) + ksq == reference bits.
//  - all plain rn (contract off); k_sq/p_sq ascending plain; pk per-lane
//    rounding == scalar. argmin: min3 strict-drop keeps first iter; even
//    key preferred on within-pair tie; lexicographic (d2,id) merges
//    (butterfly + cross-half) => numpy first-index tie-break.
//
// STRUCTURE (R12): R10/R11 died to a launch-bounds-induced spill cascade
// (min-waves 7/6 -> VGPR 36/40, GBs of scratch). This round keeps R9's
// EXACT loop (no prefetch) and R9's proven __launch_bounds__(512,4)
// (natural 64 VGPR, zero spills) and changes ONLY the LDS footprint:
// 32 KiB key-halves. HW occupancy then follows from real resources:
// LDS 4x32=128<=160 KiB, threads 2048, VGPR 8x64=512/SIMD -> 8 waves/SIMD
// (2x R9). Grid 1024 = exactly 4 blocks/CU.
__global__ __launch_bounds__(BLK, 4)
void quant_scan_kernel(const float* __restrict__ pc,
                       const float* __restrict__ keys,
                       float* __restrict__ bdws,
                       int* __restrict__ bmws)
{
#pragma clang fp contract(off)
    __shared__ float4 skA[HPAIR];  // (-2kx_e,-2kx_o,-2ky_e,-2ky_o) 16 KiB
    __shared__ float4 skB[HPAIR];  // (-2kz_e,-2kz_o, ksq_e, ksq_o) 16 KiB

    const int tid = threadIdx.x;
    const int pg   = blockIdx.x & (NPG - 1);   // point-group 0..511
    const int half = blockIdx.x >> 9;          // key-half 0 or 1

    // Stage this half's key pairs (2/thread). Global pair jg = half*1024+jl;
    // pair = keys 2jg (f0.x,f0.y,f1.x) and 2jg+1 (f1.y,f2.x,f2.y).
    #pragma unroll
    for (int i = 0; i < HPAIR / BLK; ++i) {
        const int jl = tid + i * BLK;
        const int jg = (half << 10) + jl;
        const float2 f0 = ((const float2*)keys)[3 * jg + 0];
        const float2 f1 = ((const float2*)keys)[3 * jg + 1];
        const float2 f2 = ((const float2*)keys)[3 * jg + 2];
        const float ksq0 = ((f0.x * f0.x) + (f0.y * f0.y)) + (f1.x * f1.x);
        const float ksq1 = ((f1.y * f1.y) + (f2.x * f2.x)) + (f2.y * f2.y);
        skA[jl] = make_float4(-2.0f * f0.x, -2.0f * f1.y,
                              -2.0f * f0.y, -2.0f * f2.x);
        skB[jl] = make_float4(-2.0f * f1.x, -2.0f * f2.y, ksq0, ksq1);
    }

    const int c = tid & (CC - 1);
    const int g = tid >> 5;                    // point-group-local 0..15
    const int p0 = pg * PPB + g * PP;          // my first point

    // Load my 8 points (24 floats = 6 float4, aligned: 3*p0 % 4 == 0).
    float arr[24];
    {
        const float4* pcv = (const float4*)(pc + 3 * p0);
        #pragma unroll
        for (int i = 0; i < 6; ++i) ((float4*)arr)[i] = pcv[i];
    }
    v2f PX[PP], PY[PP], PZ[PP], PSQ[PP];
    float bd[PP];
    int bk[PP];
    #pragma unroll
    for (int i = 0; i < PP; ++i) {
        const float px = arr[3 * i + 0];
        const float py = arr[3 * i + 1];
        const float pz = arr[3 * i + 2];
        const float psq = ((px * px) + (py * py)) + (pz * pz);
        PX[i] = (v2f){px, px};
        PY[i] = (v2f){py, py};
        PZ[i] = (v2f){pz, pz};
        PSQ[i] = (v2f){psq, psq};
        bd[i] = 3.402823466e38f;
        bk[i] = 0;
    }

    __syncthreads();

    // Main loop over this half: lane c, iter k -> local pair jl = 32k + c
    // (R9's exact loop body — direct LDS reads, no prefetch).
    #pragma unroll 2
    for (int k = 0; k < KIT; ++k) {
        const int j = (k << 5) + c;
        const float4 A  = skA[j];
        const float4 Bv = skB[j];
        const v2f Kx = {A.x,  A.y};
        const v2f Ky = {A.z,  A.w};
        const v2f Kz = {Bv.x, Bv.y};
        const v2f Ks = {Bv.z, Bv.w};
        #pragma unroll
        for (int i = 0; i < PP; ++i) {
            v2f t = pk_add(pk_mul(Kx, PX[i]), pk_mul(Ky, PY[i]));
            t = pk_add(t, pk_mul(Kz, PZ[i]));
            t = pk_add(PSQ[i], t);       // psq - 2*cross (keys negated)
            t = pk_add(t, Ks);           // + ksq
            const float nb = min3f(bd[i], t.x, t.y);
            const bool ch = nb < bd[i];  // strict drop => first-index kept
            bd[i] = nb;
            bk[i] = ch ? k : bk[i];
        }
    }

    // Recover winning key within pair bk[i] (scalar plain == pk bits), then
    // butterfly-merge the 32 lanes; lane 0 writes this half's champion.
    #pragma unroll
    for (int i = 0; i < PP; ++i) {
        const int jl = (bk[i] << 5) + c;
        const float4 Ar = skA[jl];
        const float4 Br = skB[jl];
        const float ca = ((PX[i].x * Ar.x) + (PY[i].x * Ar.z)) + (PZ[i].x * Br.x);
        const float da = (PSQ[i].x + ca) + Br.z;
        const int m0 = (((half << 10) + jl) << 1);
        float d = bd[i];
        int   m = (da == bd[i]) ? m0 : (m0 + 1);  // even preferred on tie
        #pragma unroll
        for (int off = 1; off < CC; off <<= 1) {
            const float od = __shfl_xor(d, off);
            const int   om = __shfl_xor(m, off);
            if (od < d || (od == d && om < m)) { d = od; m = om; }
        }
        if (c == 0) {
            bdws[half * BN + p0 + i] = d;
            bmws[half * BN + p0 + i] = m;
        }
    }
}

// Kernel 2: merge the two halves (exact fp32 lexicographic), gather value
// rows, write feats + ids, and copy the pc passthrough.
__global__ __launch_bounds__(256)
void merge_gather_kernel(const float* __restrict__ pc,
                         const float* __restrict__ values,
                         const float* __restrict__ bdws,
                         const int* __restrict__ bmws,
                         float* __restrict__ out)
{
    const int tid = threadIdx.x;
    const int c = tid & 15;                       // lane within point
    const int p = blockIdx.x * 16 + (tid >> 4);   // point id

    const float d0 = bdws[p];
    const float d1 = bdws[BN + p];
    const int   m0 = bmws[p];
    const int   m1 = bmws[BN + p];
    // Half-0 ids are all smaller than half-1 ids, so on exact tie keep m0.
    const int m = (d1 < d0) ? m1 : m0;

    const float4 v = ((const float4*)(values + (size_t)m * DD))[c];
    ((float4*)(out + FEATS_OFF + (size_t)p * DD))[c] = v;
    if (c == 0) out[IDS_OFF + p] = (float)m;

    // pc passthrough: 196608 floats = 49152 float4 spread over the grid.
    const int gt = blockIdx.x * 256 + tid;
    if (gt < BN * 3 / 4) {
        ((float4*)(out + PC_OFF))[gt] = ((const float4*)pc)[gt];
    }
}

extern "C" void kernel_launch(void* const* d_in, const int* in_sizes, int n_in,
                              void* d_out, int out_size, void* d_ws, size_t ws_size,
                              hipStream_t stream) {
    const float* pc     = (const float*)d_in[0];
    const float* keys   = (const float*)d_in[1];
    const float* values = (const float*)d_in[2];
    float* out = (float*)d_out;

    float* bdws = (float*)d_ws;                  // 2*BN floats
    int*   bmws = (int*)d_ws + 2 * BN;           // 2*BN ints   (1 MB total)

    quant_scan_kernel<<<dim3(2 * NPG), dim3(BLK), 0, stream>>>(pc, keys, bdws, bmws);
    merge_gather_kernel<<<dim3(BN / 16), dim3(256), 0, stream>>>(pc, values, bdws, bmws, out);
}